// Round 1
// baseline (284.175 us; speedup 1.0000x reference)
//
#include <hip/hip_runtime.h>
#include <math.h>

#define NQ      14
#define NSTATE  16384
#define BATCH   128
#define NGATES  26
#define DEPTH   3
#define NOBS    11
#define KDIM    16
#define NOFF    120
#define INDIM   784
#define OUTDIM  10

// LDS skew: logical float index a -> physical a + (a>>5). Breaks power-of-2
// stride bank conflicts (stride-16 pattern would otherwise be 32-way).
__device__ __forceinline__ int F(int a) { return a + (a >> 5); }
#define LDS_PHYS (NSTATE + (NSTATE >> 5))   // 16896

// ---------------------------------------------------------------------------
// Kernel A1: encoding. encoded[b, g*15+m] = x[b,:]·W_enc[g*15+m,:] + b_enc.
// One wave per (g,b) pair; lanes split j-dim; butterfly reduce 15 accumulators.
// ---------------------------------------------------------------------------
__global__ __launch_bounds__(256) void enc_kernel(
    const float* __restrict__ x, const float* __restrict__ W,
    const float* __restrict__ bvec, float* __restrict__ theta)
{
  int wave = (blockIdx.x * 256 + threadIdx.x) >> 6;   // 0..3327 = g*128 + b
  int lane = threadIdx.x & 63;
  int g = wave >> 7;
  int b = wave & 127;
  const float* xb = x + b * INDIM;
  const float* Wg = W + g * 15 * INDIM;
  float acc[15];
#pragma unroll
  for (int m = 0; m < 15; ++m) acc[m] = 0.f;
  for (int j = lane; j < INDIM; j += 64) {
    float xv = xb[j];
#pragma unroll
    for (int m = 0; m < 15; ++m) acc[m] = fmaf(xv, Wg[m * INDIM + j], acc[m]);
  }
#pragma unroll
  for (int m = 0; m < 15; ++m) {
#pragma unroll
    for (int off = 32; off; off >>= 1) acc[m] += __shfl_xor(acc[m], off);
  }
  if (lane == 0) {
#pragma unroll
    for (int m = 0; m < 15; ++m) theta[wave * 15 + m] = acc[m] + bvec[g * 15 + m];
  }
}

// ---------------------------------------------------------------------------
// Kernel A2: U = expm(i * sum_m theta_m P_m), one thread per (g,b).
// Scaling & squaring + order-9 Taylor (Horner).
// ---------------------------------------------------------------------------
__global__ __launch_bounds__(256) void expm_kernel(
    const float* __restrict__ theta, float2* __restrict__ Ubuf)
{
  int pair = blockIdx.x * 256 + threadIdx.x;          // 0..3327
  const float* th = theta + pair * 15;

  // Pauli 2x2 tables (I,X,Y,Z), entry [i*2+j]
  const float pr_[4][4] = {{1,0,0,1},{0,1,1,0},{0,0,0,0},{1,0,0,-1}};
  const float pi_[4][4] = {{0,0,0,0},{0,0,0,0},{0,-1,1,0},{0,0,0,0}};

  float Hre[16], Him[16];
#pragma unroll
  for (int e = 0; e < 16; ++e) { Hre[e] = 0.f; Him[e] = 0.f; }
  float tsum = 0.f;
#pragma unroll
  for (int m = 0; m < 15; ++m) {
    float tv = th[m];
    tsum += fabsf(tv);
    const int code = m + 1;
    const int a = code >> 2, c = code & 3;
#pragma unroll
    for (int i = 0; i < 4; ++i) {
#pragma unroll
      for (int j = 0; j < 4; ++j) {
        float ar = pr_[a][(i >> 1) * 2 + (j >> 1)], ai = pi_[a][(i >> 1) * 2 + (j >> 1)];
        float br = pr_[c][(i & 1) * 2 + (j & 1)],   bi = pi_[c][(i & 1) * 2 + (j & 1)];
        Hre[i * 4 + j] += tv * (ar * br - ai * bi);
        Him[i * 4 + j] += tv * (ar * bi + ai * br);
      }
    }
  }

  int s = 0;
  if (tsum > 0.25f) {
    s = (int)ceilf(log2f(tsum * 4.0f));
    if (s < 0) s = 0;
    if (s > 14) s = 14;
  }
  float sc = exp2f((float)(-s));

  // G = i*H*sc
  float Gre[16], Gim[16];
#pragma unroll
  for (int e = 0; e < 16; ++e) { Gre[e] = -Him[e] * sc; Gim[e] = Hre[e] * sc; }

  // T = I + G/9; then T = I + (G/k)T for k=8..1
  float Tre[16], Tim[16];
#pragma unroll
  for (int e = 0; e < 16; ++e) {
    Tre[e] = Gre[e] * (1.f / 9.f) + ((e % 5 == 0) ? 1.f : 0.f);
    Tim[e] = Gim[e] * (1.f / 9.f);
  }
  for (int k = 8; k >= 1; --k) {
    float nr[16], ni[16];
    float invk = 1.0f / (float)k;
#pragma unroll
    for (int i = 0; i < 4; ++i) {
#pragma unroll
      for (int j = 0; j < 4; ++j) {
        float xr = 0.f, xi = 0.f;
#pragma unroll
        for (int l = 0; l < 4; ++l) {
          xr += Gre[i * 4 + l] * Tre[l * 4 + j] - Gim[i * 4 + l] * Tim[l * 4 + j];
          xi += Gre[i * 4 + l] * Tim[l * 4 + j] + Gim[i * 4 + l] * Tre[l * 4 + j];
        }
        nr[i * 4 + j] = invk * xr + ((i == j) ? 1.f : 0.f);
        ni[i * 4 + j] = invk * xi;
      }
    }
#pragma unroll
    for (int e = 0; e < 16; ++e) { Tre[e] = nr[e]; Tim[e] = ni[e]; }
  }
  // square s times
  for (int it = 0; it < s; ++it) {
    float nr[16], ni[16];
#pragma unroll
    for (int i = 0; i < 4; ++i) {
#pragma unroll
      for (int j = 0; j < 4; ++j) {
        float xr = 0.f, xi = 0.f;
#pragma unroll
        for (int l = 0; l < 4; ++l) {
          xr += Tre[i * 4 + l] * Tre[l * 4 + j] - Tim[i * 4 + l] * Tim[l * 4 + j];
          xi += Tre[i * 4 + l] * Tim[l * 4 + j] + Tim[i * 4 + l] * Tre[l * 4 + j];
        }
        nr[i * 4 + j] = xr; ni[i * 4 + j] = xi;
      }
    }
#pragma unroll
    for (int e = 0; e < 16; ++e) { Tre[e] = nr[e]; Tim[e] = ni[e]; }
  }
#pragma unroll
  for (int e = 0; e < 16; ++e) Ubuf[pair * 16 + e] = make_float2(Tre[e], Tim[e]);
}

// ---------------------------------------------------------------------------
// Kernel B: full statevector simulation in LDS, one block per batch element.
// ---------------------------------------------------------------------------
__global__ __launch_bounds__(1024) void qsim_kernel(
    const float2* __restrict__ U, const float* __restrict__ var_params,
    const float* __restrict__ A, const float* __restrict__ Bp,
    const float* __restrict__ D, const float* __restrict__ Wh,
    const float* __restrict__ bh, float* __restrict__ out)
{
  __shared__ float sRe[LDS_PHYS];
  __shared__ float sIm[LDS_PHYS];
  __shared__ float Ml[21 * 16];
  __shared__ float obsb[256];
  __shared__ float red[16];
  __shared__ float qv[NOBS];

  const int t = threadIdx.x;
  const int b = blockIdx.x;

  for (int i = t; i < LDS_PHYS; i += 1024) { sRe[i] = 0.f; sIm[i] = 0.f; }
  if (t == 0) sRe[0] = 1.f;   // F(0)==0; |00..0>

  // fused variational matrices: M = CNOT * (RY(q) ⊗ RY(q+1)) for even pairs
  if (t < 21) {
    int l = t / 7, jj = t % 7, q = 2 * jj;
    float h0 = var_params[l * NQ + q] * 0.5f;
    float h1 = var_params[l * NQ + q + 1] * 0.5f;
    float c0 = cosf(h0), s0 = sinf(h0), c1 = cosf(h1), s1 = sinf(h1);
    float R0[4] = {c0, -s0, s0, c0};
    float R1[4] = {c1, -s1, s1, c1};
    float M[16];
#pragma unroll
    for (int a = 0; a < 2; ++a)
#pragma unroll
      for (int bb = 0; bb < 2; ++bb)
#pragma unroll
        for (int c = 0; c < 2; ++c)
#pragma unroll
          for (int d = 0; d < 2; ++d)
            M[(a * 2 + bb) * 4 + (c * 2 + d)] = R0[a * 2 + c] * R1[bb * 2 + d];
#pragma unroll
    for (int c = 0; c < 4; ++c) { float tmp = M[8 + c]; M[8 + c] = M[12 + c]; M[12 + c] = tmp; }
#pragma unroll
    for (int e = 0; e < 16; ++e) Ml[t * 16 + e] = M[e];
  }
  __syncthreads();

  // ---- 26 SU(4) encoding gates ----
  for (int g = 0; g < NGATES; ++g) {
    int g13 = g % 13;
    int q = (g13 < 7) ? (2 * g13) : (2 * (g13 - 7) + 1);
    int p = 12 - q;
    int S = 1 << p;
    const float2* ug = U + (g * BATCH + b) * 16;
    float ur[16], ui[16];
#pragma unroll
    for (int e = 0; e < 16; ++e) { float2 v = ug[e]; ur[e] = v.x; ui[e] = v.y; }
#pragma unroll
    for (int it = 0; it < 4; ++it) {
      int m = t + it * 1024;
      int base = ((m >> p) << (p + 2)) | (m & (S - 1));
      int ad[4] = {F(base), F(base + S), F(base + 2 * S), F(base + 3 * S)};
      float rr[4], ii[4];
#pragma unroll
      for (int j = 0; j < 4; ++j) { rr[j] = sRe[ad[j]]; ii[j] = sIm[ad[j]]; }
      float outr[4], outi[4];
#pragma unroll
      for (int i = 0; i < 4; ++i) {
        float xr = 0.f, xi = 0.f;
#pragma unroll
        for (int j = 0; j < 4; ++j) {
          xr += ur[i * 4 + j] * rr[j] - ui[i * 4 + j] * ii[j];
          xi += ur[i * 4 + j] * ii[j] + ui[i * 4 + j] * rr[j];
        }
        outr[i] = xr; outi[i] = xi;
      }
#pragma unroll
      for (int j = 0; j < 4; ++j) { sRe[ad[j]] = outr[j]; sIm[ad[j]] = outi[j]; }
    }
    __syncthreads();
  }

  // ---- 3 variational layers: fused RY⊗RY·CNOT on even pairs, then odd CNOTs
  for (int l = 0; l < DEPTH; ++l) {
    for (int jj = 0; jj < 7; ++jj) {
      int q = 2 * jj, p = 12 - q, S = 1 << p;
      float Mv[16];
#pragma unroll
      for (int e = 0; e < 16; ++e) Mv[e] = Ml[(l * 7 + jj) * 16 + e];
#pragma unroll
      for (int it = 0; it < 4; ++it) {
        int m = t + it * 1024;
        int base = ((m >> p) << (p + 2)) | (m & (S - 1));
        int ad[4] = {F(base), F(base + S), F(base + 2 * S), F(base + 3 * S)};
        float rr[4], ii[4];
#pragma unroll
        for (int j = 0; j < 4; ++j) { rr[j] = sRe[ad[j]]; ii[j] = sIm[ad[j]]; }
        float outr[4], outi[4];
#pragma unroll
        for (int i = 0; i < 4; ++i) {
          float xr = 0.f, xi = 0.f;
#pragma unroll
          for (int j = 0; j < 4; ++j) {
            xr += Mv[i * 4 + j] * rr[j];
            xi += Mv[i * 4 + j] * ii[j];
          }
          outr[i] = xr; outi[i] = xi;
        }
#pragma unroll
        for (int j = 0; j < 4; ++j) { sRe[ad[j]] = outr[j]; sIm[ad[j]] = outi[j]; }
      }
      __syncthreads();
    }
    for (int jj = 0; jj < 6; ++jj) {
      int q = 2 * jj + 1, p = 12 - q, S = 1 << p;
#pragma unroll
      for (int it = 0; it < 4; ++it) {
        int m = t + it * 1024;
        int base = ((m >> p) << (p + 2)) | (m & (S - 1));
        int a2 = F(base + 2 * S), a3 = F(base + 3 * S);
        float r2 = sRe[a2], i2 = sIm[a2], r3 = sRe[a3], i3 = sIm[a3];
        sRe[a2] = r3; sIm[a2] = i3; sRe[a3] = r2; sIm[a3] = i2;
      }
      __syncthreads();
    }
  }

  // ---- 11 Hermitian expectation values ----
  for (int w = 0; w < NOBS; ++w) {
    // stage observable params into LDS (broadcast reads later)
    if (t < NOFF) obsb[t] = A[w * NOFF + t];
    else if (t < 2 * NOFF) obsb[t] = Bp[w * NOFF + (t - NOFF)];
    else if (t < 256) obsb[t] = D[w * KDIM + (t - 2 * NOFF)];
    __syncthreads();

    int shift = 10 - w;
    int hi = t >> shift;
    int lo = t & ((1 << shift) - 1);
    int baseaddr = (hi << (shift + 4)) | lo;
    float sr[16], si[16];
#pragma unroll
    for (int k = 0; k < 16; ++k) {
      int a = F(baseaddr + (k << shift));
      sr[k] = sRe[a]; si[k] = sIm[a];
    }
    float E = 0.f;
#pragma unroll
    for (int k = 0; k < 15; ++k)
      E = fmaf(obsb[240 + k + 1], sr[k] * sr[k] + si[k] * si[k], E);
#pragma unroll
    for (int k = 1; k < 16; ++k) {
#pragma unroll
      for (int l2 = 0; l2 < k; ++l2) {
        const int pidx = (k * (k - 1)) / 2 + l2;
        float t1 = sr[k] * sr[l2] + si[k] * si[l2];
        float t2 = si[k] * sr[l2] - sr[k] * si[l2];
        E = fmaf(obsb[pidx], t1, fmaf(obsb[NOFF + pidx], t2, E));
      }
    }
    E *= 2.0f;
#pragma unroll
    for (int off = 32; off; off >>= 1) E += __shfl_xor(E, off);
    if ((t & 63) == 0) red[t >> 6] = E;
    __syncthreads();
    if (t == 0) {
      float sum = 0.f;
      for (int ww = 0; ww < 16; ++ww) sum += red[ww];
      qv[w] = sum;
    }
    __syncthreads();
  }

  // ---- head ----
  if (t < OUTDIM) {
    float o = bh[t];
#pragma unroll
    for (int w = 0; w < NOBS; ++w) o = fmaf(Wh[t * NOBS + w], qv[w], o);
    out[b * OUTDIM + t] = o;
  }
}

extern "C" void kernel_launch(void* const* d_in, const int* in_sizes, int n_in,
                              void* d_out, int out_size, void* d_ws, size_t ws_size,
                              hipStream_t stream) {
  const float* x          = (const float*)d_in[0];
  const float* W_enc      = (const float*)d_in[1];
  const float* b_enc      = (const float*)d_in[2];
  const float* var_params = (const float*)d_in[3];
  const float* A          = (const float*)d_in[4];
  const float* Bp         = (const float*)d_in[5];
  const float* D          = (const float*)d_in[6];
  const float* W_head     = (const float*)d_in[7];
  const float* b_head     = (const float*)d_in[8];
  float* out = (float*)d_out;

  float*  theta = (float*)d_ws;                                   // 3328*15 f32
  size_t  thBytes = (size_t)3328 * 15 * sizeof(float);
  float2* Ubuf = (float2*)((char*)d_ws + ((thBytes + 255) / 256) * 256);

  enc_kernel<<<832, 256, 0, stream>>>(x, W_enc, b_enc, theta);
  expm_kernel<<<13, 256, 0, stream>>>(theta, Ubuf);
  qsim_kernel<<<128, 1024, 0, stream>>>(Ubuf, var_params, A, Bp, D,
                                        W_head, b_head, out);
}

// Round 2
// 241.076 us; speedup vs baseline: 1.1788x; 1.1788x over previous
//
#include <hip/hip_runtime.h>
#include <math.h>

#define NQ      14
#define NSTATE  16384
#define BATCH   128
#define DEPTH   3
#define NOBS    11
#define KDIM    16
#define NOFF    120
#define INDIM   784
#define OUTDIM  10

// skew on complex index: logical a -> physical a + (a>>4) (float2 units)
__device__ __forceinline__ int F2(int a) { return a + (a >> 4); }
#define PHYS2 (NSTATE + (NSTATE >> 4))   // 17408 float2 = 136 KB

// force block-uniform value into SGPR
__device__ __forceinline__ float sbc(float x) {
  return __int_as_float(__builtin_amdgcn_readfirstlane(__float_as_int(x)));
}

// ---------------------------------------------------------------------------
// Kernel 1: encoding GEMM + expm fused. One wave per (g,b) pair.
// ---------------------------------------------------------------------------
__global__ __launch_bounds__(256) void enc_expm_kernel(
    const float* __restrict__ x, const float* __restrict__ W,
    const float* __restrict__ bvec, float2* __restrict__ Ubuf)
{
  int wave = ((blockIdx.x << 2) | (threadIdx.x >> 6));   // 0..3327
  int lane = threadIdx.x & 63;
  int g = wave >> 7;
  int b = wave & 127;

  const float4* x4 = (const float4*)(x + (size_t)b * INDIM);        // 196
  const float4* w4 = (const float4*)(W + (size_t)g * 15 * INDIM);   // rows of 196

  float acc[15];
#pragma unroll
  for (int m = 0; m < 15; ++m) acc[m] = 0.f;
  for (int it = 0; it < 4; ++it) {
    int j4 = lane + it * 64;
    if (j4 < 196) {
      float4 xv = x4[j4];
#pragma unroll
      for (int m = 0; m < 15; ++m) {
        float4 wv = w4[m * 196 + j4];
        acc[m] = fmaf(xv.x, wv.x, fmaf(xv.y, wv.y, fmaf(xv.z, wv.z, fmaf(xv.w, wv.w, acc[m]))));
      }
    }
  }
#pragma unroll
  for (int m = 0; m < 15; ++m) {
#pragma unroll
    for (int off = 32; off; off >>= 1) acc[m] += __shfl_xor(acc[m], off);
  }
  float th[15];
#pragma unroll
  for (int m = 0; m < 15; ++m) th[m] = acc[m] + bvec[g * 15 + m];

  // ---- expm(i * sum th_m P_m), all lanes redundantly ----
  const float pr_[4][4] = {{1,0,0,1},{0,1,1,0},{0,0,0,0},{1,0,0,-1}};
  const float pi_[4][4] = {{0,0,0,0},{0,0,0,0},{0,-1,1,0},{0,0,0,0}};
  float Hre[16], Him[16];
#pragma unroll
  for (int e = 0; e < 16; ++e) { Hre[e] = 0.f; Him[e] = 0.f; }
  float tsum = 0.f;
#pragma unroll
  for (int m = 0; m < 15; ++m) {
    float tv = th[m];
    tsum += fabsf(tv);
    const int code = m + 1;
    const int a = code >> 2, c = code & 3;
#pragma unroll
    for (int i = 0; i < 4; ++i)
#pragma unroll
      for (int j = 0; j < 4; ++j) {
        float ar = pr_[a][(i >> 1) * 2 + (j >> 1)], ai = pi_[a][(i >> 1) * 2 + (j >> 1)];
        float br = pr_[c][(i & 1) * 2 + (j & 1)],   bi = pi_[c][(i & 1) * 2 + (j & 1)];
        Hre[i * 4 + j] += tv * (ar * br - ai * bi);
        Him[i * 4 + j] += tv * (ar * bi + ai * br);
      }
  }
  int s = 0;
  if (tsum > 0.25f) {
    s = (int)ceilf(log2f(tsum * 4.0f));
    if (s < 0) s = 0;
    if (s > 14) s = 14;
  }
  float sc = exp2f((float)(-s));
  float Gre[16], Gim[16];
#pragma unroll
  for (int e = 0; e < 16; ++e) { Gre[e] = -Him[e] * sc; Gim[e] = Hre[e] * sc; }
  float Tre[16], Tim[16];
#pragma unroll
  for (int e = 0; e < 16; ++e) {
    Tre[e] = Gre[e] * (1.f / 9.f) + ((e % 5 == 0) ? 1.f : 0.f);
    Tim[e] = Gim[e] * (1.f / 9.f);
  }
  for (int k = 8; k >= 1; --k) {
    float nr[16], ni[16];
    float invk = 1.0f / (float)k;
#pragma unroll
    for (int i = 0; i < 4; ++i)
#pragma unroll
      for (int j = 0; j < 4; ++j) {
        float xr = 0.f, xi = 0.f;
#pragma unroll
        for (int l = 0; l < 4; ++l) {
          xr += Gre[i * 4 + l] * Tre[l * 4 + j] - Gim[i * 4 + l] * Tim[l * 4 + j];
          xi += Gre[i * 4 + l] * Tim[l * 4 + j] + Gim[i * 4 + l] * Tre[l * 4 + j];
        }
        nr[i * 4 + j] = invk * xr + ((i == j) ? 1.f : 0.f);
        ni[i * 4 + j] = invk * xi;
      }
#pragma unroll
    for (int e = 0; e < 16; ++e) { Tre[e] = nr[e]; Tim[e] = ni[e]; }
  }
  for (int it = 0; it < s; ++it) {
    float nr[16], ni[16];
#pragma unroll
    for (int i = 0; i < 4; ++i)
#pragma unroll
      for (int j = 0; j < 4; ++j) {
        float xr = 0.f, xi = 0.f;
#pragma unroll
        for (int l = 0; l < 4; ++l) {
          xr += Tre[i * 4 + l] * Tre[l * 4 + j] - Tim[i * 4 + l] * Tim[l * 4 + j];
          xi += Tre[i * 4 + l] * Tim[l * 4 + j] + Tim[i * 4 + l] * Tre[l * 4 + j];
        }
        nr[i * 4 + j] = xr; ni[i * 4 + j] = xi;
      }
#pragma unroll
    for (int e = 0; e < 16; ++e) { Tre[e] = nr[e]; Tim[e] = ni[e]; }
  }
  if (lane == 0) {
#pragma unroll
    for (int e = 0; e < 16; ++e)
      Ubuf[(size_t)wave * 16 + e] = make_float2(Tre[e], Tim[e]);
  }
}

// ---------------------------------------------------------------------------
// qsim helpers: 16-amp register groups over 4 contiguous state bits [S+3..S]
// ---------------------------------------------------------------------------
template<int S>
__device__ __forceinline__ int grpbase(int t) {
  return ((t >> S) << (S + 4)) | (t & ((1 << S) - 1));
}
template<int S>
__device__ __forceinline__ void ldgrp(const float2* st, int base, float* vr, float* vi) {
#pragma unroll
  for (int k = 0; k < 16; ++k) {
    float2 v = st[F2(base + (k << S))];
    vr[k] = v.x; vi[k] = v.y;
  }
}
template<int S>
__device__ __forceinline__ void stgrp(float2* st, int base, const float* vr, const float* vi) {
#pragma unroll
  for (int k = 0; k < 16; ++k) st[F2(base + (k << S))] = make_float2(vr[k], vi[k]);
}

__device__ __forceinline__ void loadU(const float2* __restrict__ Ug, float* ur, float* ui) {
#pragma unroll
  for (int e = 0; e < 16; ++e) {
    float2 u = Ug[e];
    ur[e] = sbc(u.x); ui[e] = sbc(u.y);
  }
}

// gate on HIGH bit-pair (k>>2): quads {v[j2], v[4+j2], v[8+j2], v[12+j2]}
__device__ __forceinline__ void applyU_hi(float* vr, float* vi, const float* ur, const float* ui) {
#pragma unroll
  for (int j2 = 0; j2 < 4; ++j2) {
    float ar[4], ai[4];
#pragma unroll
    for (int j = 0; j < 4; ++j) { ar[j] = vr[4 * j + j2]; ai[j] = vi[4 * j + j2]; }
#pragma unroll
    for (int i = 0; i < 4; ++i) {
      float xr = 0.f, xi = 0.f;
#pragma unroll
      for (int j = 0; j < 4; ++j) {
        xr = fmaf(ur[4 * i + j], ar[j], xr);
        xr = fmaf(-ui[4 * i + j], ai[j], xr);
        xi = fmaf(ur[4 * i + j], ai[j], xi);
        xi = fmaf(ui[4 * i + j], ar[j], xi);
      }
      vr[4 * i + j2] = xr; vi[4 * i + j2] = xi;
    }
  }
}
// gate on LOW bit-pair (k&3): quads {v[4*i2+0..3]}
__device__ __forceinline__ void applyU_lo(float* vr, float* vi, const float* ur, const float* ui) {
#pragma unroll
  for (int i2 = 0; i2 < 4; ++i2) {
    float ar[4], ai[4];
#pragma unroll
    for (int j = 0; j < 4; ++j) { ar[j] = vr[4 * i2 + j]; ai[j] = vi[4 * i2 + j]; }
#pragma unroll
    for (int i = 0; i < 4; ++i) {
      float xr = 0.f, xi = 0.f;
#pragma unroll
      for (int j = 0; j < 4; ++j) {
        xr = fmaf(ur[4 * i + j], ar[j], xr);
        xr = fmaf(-ui[4 * i + j], ai[j], xr);
        xi = fmaf(ur[4 * i + j], ai[j], xi);
        xi = fmaf(ui[4 * i + j], ar[j], xi);
      }
      vr[4 * i2 + i] = xr; vi[4 * i2 + i] = xi;
    }
  }
}

template<int B>
__device__ __forceinline__ void ry16(float* vr, float* vi, float c, float s) {
#pragma unroll
  for (int k = 0; k < 16; ++k) {
    if (!(k & (1 << B))) {
      const int k1 = k | (1 << B);
      float r0 = vr[k], i0 = vi[k], r1 = vr[k1], i1 = vi[k1];
      vr[k]  = fmaf(c, r0, -s * r1);  vi[k]  = fmaf(c, i0, -s * i1);
      vr[k1] = fmaf(s, r0,  c * r1);  vi[k1] = fmaf(s, i0,  c * i1);
    }
  }
}
template<int CB, int TB>
__device__ __forceinline__ void cx16(float* vr, float* vi) {
#pragma unroll
  for (int k = 0; k < 16; ++k) {
    if ((k & (1 << CB)) && !(k & (1 << TB))) {
      const int k1 = k | (1 << TB);
      float tr = vr[k]; vr[k] = vr[k1]; vr[k1] = tr;
      float ti = vi[k]; vi[k] = vi[k1]; vi[k1] = ti;
    }
  }
}

template<int S>
__device__ __forceinline__ void enc_pass2(float2* st, const float2* __restrict__ U,
                                          int g1, int g2, int b, int t) {
  float ur[16], ui[16], vr[16], vi[16];
  int base = grpbase<S>(t);
  ldgrp<S>(st, base, vr, vi);
  loadU(U + ((size_t)g1 * BATCH + b) * 16, ur, ui);
  applyU_hi(vr, vi, ur, ui);
  loadU(U + ((size_t)g2 * BATCH + b) * 16, ur, ui);
  applyU_lo(vr, vi, ur, ui);
  stgrp<S>(st, base, vr, vi);
}
__device__ __forceinline__ void enc_pass1(float2* st, const float2* __restrict__ U,
                                          int g, int b, int t) {
  float ur[16], ui[16], vr[16], vi[16];
  int base = t << 4;
  ldgrp<0>(st, base, vr, vi);
  loadU(U + ((size_t)g * BATCH + b) * 16, ur, ui);
  applyU_lo(vr, vi, ur, ui);
  stgrp<0>(st, base, vr, vi);
}
template<int S>
__device__ __forceinline__ void var_pass(float2* st, const float* __restrict__ vp,
                                         int l, int qbase, int t) {
  float vr[16], vi[16];
  int base = grpbase<S>(t);
  ldgrp<S>(st, base, vr, vi);
  float c[4], sn[4];
#pragma unroll
  for (int i = 0; i < 4; ++i) {
    float a = sbc(vp[l * NQ + qbase + i]) * 0.5f;
    c[i] = cosf(a); sn[i] = sinf(a);
  }
  ry16<3>(vr, vi, c[0], sn[0]);
  ry16<2>(vr, vi, c[1], sn[1]);
  ry16<1>(vr, vi, c[2], sn[2]);
  ry16<0>(vr, vi, c[3], sn[3]);
  cx16<3, 2>(vr, vi);
  cx16<1, 0>(vr, vi);
  stgrp<S>(st, base, vr, vi);
}
__device__ __forceinline__ void var_lone(float2* st, const float* __restrict__ vp, int l, int t) {
  float vr[16], vi[16];
  int base = t << 4;
  ldgrp<0>(st, base, vr, vi);
  float a0 = sbc(vp[l * NQ + 12]) * 0.5f;
  float a1 = sbc(vp[l * NQ + 13]) * 0.5f;
  ry16<1>(vr, vi, cosf(a0), sinf(a0));
  ry16<0>(vr, vi, cosf(a1), sinf(a1));
  cx16<1, 0>(vr, vi);
  stgrp<0>(st, base, vr, vi);
}
// two CNOTs: ctrl bit3 -> tgt bit2, ctrl bit1 -> tgt bit0 (pure LDS swaps)
template<int S>
__device__ __forceinline__ void odd_cnot(float2* st, int t) {
  int base = grpbase<S>(t);
#pragma unroll
  for (int k = 0; k < 16; ++k) {
    const int sk = k ^ (((k >> 3) & 1) << 2) ^ ((k >> 1) & 1);
    if (sk > k) {
      int a0 = F2(base + (k << S)), a1 = F2(base + (sk << S));
      float2 x0 = st[a0], x1 = st[a1];
      st[a0] = x1; st[a1] = x0;
    }
  }
}

// ---------------------------------------------------------------------------
// Kernel 2: full statevector sim, one block per batch element.
// ---------------------------------------------------------------------------
__global__ __launch_bounds__(1024) void qsim_kernel(
    const float2* __restrict__ U, const float* __restrict__ var_params,
    const float* __restrict__ A, const float* __restrict__ Bp,
    const float* __restrict__ D, const float* __restrict__ Wh,
    const float* __restrict__ bh, float* __restrict__ out)
{
  __shared__ float2 st[PHYS2];
  __shared__ float obsb[256];
  __shared__ float red[16];
  __shared__ float qv[NOBS];

  const int t = threadIdx.x;
  const int b = blockIdx.x;

  for (int i = t; i < PHYS2; i += 1024) st[i] = make_float2(0.f, 0.f);
  __syncthreads();
  if (t == 0) st[0] = make_float2(1.f, 0.f);
  __syncthreads();

  // ---- encoding: 2 blocks x (even sweep fused 2+2+2+1, odd sweep 2+2+2) ----
  for (int nb = 0; nb < 2; ++nb) {
    int gI = nb * 13;
    enc_pass2<10>(st, U, gI + 0,  gI + 1,  b, t); __syncthreads();
    enc_pass2<6 >(st, U, gI + 2,  gI + 3,  b, t); __syncthreads();
    enc_pass2<2 >(st, U, gI + 4,  gI + 5,  b, t); __syncthreads();
    enc_pass1    (st, U, gI + 6,           b, t); __syncthreads();
    enc_pass2<9 >(st, U, gI + 7,  gI + 8,  b, t); __syncthreads();
    enc_pass2<5 >(st, U, gI + 9,  gI + 10, b, t); __syncthreads();
    enc_pass2<1 >(st, U, gI + 11, gI + 12, b, t); __syncthreads();
  }

  // ---- variational: RY + even CNOT fused in-register; odd CNOT swaps ----
  for (int l = 0; l < DEPTH; ++l) {
    var_pass<10>(st, var_params, l, 0, t); __syncthreads();
    var_pass<6 >(st, var_params, l, 4, t); __syncthreads();
    var_pass<2 >(st, var_params, l, 8, t); __syncthreads();
    var_lone    (st, var_params, l,    t); __syncthreads();
    odd_cnot<9>(st, t); __syncthreads();
    odd_cnot<5>(st, t); __syncthreads();
    odd_cnot<1>(st, t); __syncthreads();
  }

  // ---- 11 Hermitian expectation values ----
  for (int w = 0; w < NOBS; ++w) {
    if (t < NOFF) obsb[t] = A[w * NOFF + t];
    else if (t < 2 * NOFF) obsb[t] = Bp[w * NOFF + (t - NOFF)];
    else if (t < 2 * NOFF + KDIM) obsb[t] = D[w * KDIM + (t - 2 * NOFF)];
    __syncthreads();

    int shift = 10 - w;
    int hi = t >> shift;
    int lo = t & ((1 << shift) - 1);
    int base2 = (hi << (shift + 4)) | lo;
    float sr[16], si[16];
#pragma unroll
    for (int k = 0; k < 16; ++k) {
      float2 v = st[F2(base2 + (k << shift))];
      sr[k] = v.x; si[k] = v.y;
    }
    float E = 0.f;
#pragma unroll
    for (int k = 0; k < 15; ++k)
      E = fmaf(obsb[240 + k + 1], sr[k] * sr[k] + si[k] * si[k], E);
#pragma unroll
    for (int k = 1; k < 16; ++k) {
#pragma unroll
      for (int l2 = 0; l2 < k; ++l2) {
        const int pidx = (k * (k - 1)) / 2 + l2;
        float t1 = sr[k] * sr[l2] + si[k] * si[l2];
        float t2 = si[k] * sr[l2] - sr[k] * si[l2];
        E = fmaf(obsb[pidx], t1, fmaf(obsb[NOFF + pidx], t2, E));
      }
    }
    E *= 2.0f;
#pragma unroll
    for (int off = 32; off; off >>= 1) E += __shfl_xor(E, off);
    if ((t & 63) == 0) red[t >> 6] = E;
    __syncthreads();
    if (t == 0) {
      float sum = 0.f;
      for (int ww = 0; ww < 16; ++ww) sum += red[ww];
      qv[w] = sum;
    }
    __syncthreads();
  }

  // ---- head ----
  if (t < OUTDIM) {
    float o = bh[t];
#pragma unroll
    for (int w = 0; w < NOBS; ++w) o = fmaf(Wh[t * NOBS + w], qv[w], o);
    out[b * OUTDIM + t] = o;
  }
}

extern "C" void kernel_launch(void* const* d_in, const int* in_sizes, int n_in,
                              void* d_out, int out_size, void* d_ws, size_t ws_size,
                              hipStream_t stream) {
  const float* x          = (const float*)d_in[0];
  const float* W_enc      = (const float*)d_in[1];
  const float* b_enc      = (const float*)d_in[2];
  const float* var_params = (const float*)d_in[3];
  const float* A          = (const float*)d_in[4];
  const float* Bp         = (const float*)d_in[5];
  const float* D          = (const float*)d_in[6];
  const float* W_head     = (const float*)d_in[7];
  const float* b_head     = (const float*)d_in[8];
  float* out = (float*)d_out;

  float2* Ubuf = (float2*)d_ws;   // 3328 * 16 float2

  enc_expm_kernel<<<832, 256, 0, stream>>>(x, W_enc, b_enc, Ubuf);
  qsim_kernel<<<128, 1024, 0, stream>>>(Ubuf, var_params, A, Bp, D,
                                        W_head, b_head, out);
}

// Round 3
// 207.415 us; speedup vs baseline: 1.3701x; 1.1623x over previous
//
#include <hip/hip_runtime.h>
#include <math.h>

#define NQ      14
#define NSTATE  16384
#define BATCH   128
#define DEPTH   3
#define NOBS    11
#define KDIM    16
#define NOFF    120
#define INDIM   784
#define OUTDIM  10

// skew on complex index: logical a -> physical a + (a>>4) (float2 units)
__device__ __forceinline__ int F2(int a) { return a + (a >> 4); }
#define PHYS2 (NSTATE + (NSTATE >> 4))   // 17408 float2 = 136 KB

// force block-uniform value into SGPR
__device__ __forceinline__ float sbc(float x) {
  return __int_as_float(__builtin_amdgcn_readfirstlane(__float_as_int(x)));
}

// ---------------------------------------------------------------------------
// Kernel 1: encoding GEMM. One wave per (g,b) pair -> theta[g*128+b][15].
// ---------------------------------------------------------------------------
__global__ __launch_bounds__(256) void enc_kernel(
    const float* __restrict__ x, const float* __restrict__ W,
    const float* __restrict__ bvec, float* __restrict__ theta)
{
  int wave = ((blockIdx.x << 2) | (threadIdx.x >> 6));   // 0..3327
  int lane = threadIdx.x & 63;
  int g = wave >> 7;
  int b = wave & 127;

  const float4* x4 = (const float4*)(x + (size_t)b * INDIM);        // 196 f4
  const float4* w4 = (const float4*)(W + (size_t)g * 15 * INDIM);

  float acc[15];
#pragma unroll
  for (int m = 0; m < 15; ++m) acc[m] = 0.f;
#pragma unroll
  for (int it = 0; it < 4; ++it) {
    int j4 = lane + it * 64;
    if (j4 < 196) {
      float4 xv = x4[j4];
#pragma unroll
      for (int m = 0; m < 15; ++m) {
        float4 wv = w4[m * 196 + j4];
        acc[m] = fmaf(xv.x, wv.x, fmaf(xv.y, wv.y, fmaf(xv.z, wv.z, fmaf(xv.w, wv.w, acc[m]))));
      }
    }
  }
#pragma unroll
  for (int m = 0; m < 15; ++m) {
#pragma unroll
    for (int off = 32; off; off >>= 1) acc[m] += __shfl_xor(acc[m], off);
  }
  if (lane == 0) {
#pragma unroll
    for (int m = 0; m < 15; ++m) theta[(size_t)wave * 15 + m] = acc[m] + bvec[g * 15 + m];
  }
}

// ---------------------------------------------------------------------------
// Kernel 2: U = expm(i * sum th_m P_m). FOUR lanes per matrix; lane j owns
// column j of T. G replicated per lane (Horner is lane-local); squarings
// fetch columns via intra-group shuffles.
// ---------------------------------------------------------------------------
__global__ __launch_bounds__(256) void expm_kernel(
    const float* __restrict__ theta, float2* __restrict__ Ubuf)
{
  int gid  = blockIdx.x * 256 + threadIdx.x;   // 0..13311
  int pair = gid >> 2;                         // 0..3327
  int j    = gid & 3;                          // column
  int lane = threadIdx.x & 63;
  int grp  = lane & 60;

  const float* th = theta + (size_t)pair * 15;

  const float pr_[4][4] = {{1,0,0,1},{0,1,1,0},{0,0,0,0},{1,0,0,-1}};
  const float pi_[4][4] = {{0,0,0,0},{0,0,0,0},{0,-1,1,0},{0,0,0,0}};

  float Hre[16], Him[16];
#pragma unroll
  for (int e = 0; e < 16; ++e) { Hre[e] = 0.f; Him[e] = 0.f; }
  float tsum = 0.f;
#pragma unroll
  for (int m = 0; m < 15; ++m) {
    float tv = th[m];
    tsum += fabsf(tv);
    const int code = m + 1;
    const int a = code >> 2, c = code & 3;
#pragma unroll
    for (int i = 0; i < 4; ++i)
#pragma unroll
      for (int jj = 0; jj < 4; ++jj) {
        float ar = pr_[a][(i >> 1) * 2 + (jj >> 1)], ai = pi_[a][(i >> 1) * 2 + (jj >> 1)];
        float br = pr_[c][(i & 1) * 2 + (jj & 1)],   bi = pi_[c][(i & 1) * 2 + (jj & 1)];
        Hre[i * 4 + jj] += tv * (ar * br - ai * bi);
        Him[i * 4 + jj] += tv * (ar * bi + ai * br);
      }
  }
  int s = 0;
  if (tsum > 0.25f) {
    s = (int)ceilf(log2f(tsum * 4.0f));
    if (s < 0) s = 0;
    if (s > 14) s = 14;
  }
  float sc = exp2f((float)(-s));
  // G = i*H*sc (full, replicated per lane)
  float Gre[16], Gim[16];
#pragma unroll
  for (int e = 0; e < 16; ++e) { Gre[e] = -Him[e] * sc; Gim[e] = Hre[e] * sc; }

  // column-j Horner: Tc = G[:,j]/9 + e_j;  Tc = e_j + (G/k)Tc, k=8..1
  float Tcr[4], Tci[4];
#pragma unroll
  for (int i = 0; i < 4; ++i) {
    Tcr[i] = Gre[i * 4 + j] * (1.f / 9.f) + ((i == j) ? 1.f : 0.f);
    Tci[i] = Gim[i * 4 + j] * (1.f / 9.f);
  }
#pragma unroll
  for (int k = 8; k >= 1; --k) {
    float nr[4], ni[4];
    float invk = 1.0f / (float)k;
#pragma unroll
    for (int i = 0; i < 4; ++i) {
      float xr = 0.f, xi = 0.f;
#pragma unroll
      for (int l = 0; l < 4; ++l) {
        xr = fmaf(Gre[i * 4 + l], Tcr[l], fmaf(-Gim[i * 4 + l], Tci[l], xr));
        xi = fmaf(Gre[i * 4 + l], Tci[l], fmaf( Gim[i * 4 + l], Tcr[l], xi));
      }
      nr[i] = invk * xr + ((i == j) ? 1.f : 0.f);
      ni[i] = invk * xi;
    }
#pragma unroll
    for (int i = 0; i < 4; ++i) { Tcr[i] = nr[i]; Tci[i] = ni[i]; }
  }
  // square s times: new[:,j] = sum_l T[:,l] * T[l,j]
  for (int it = 0; it < s; ++it) {
    float nr[4] = {0.f, 0.f, 0.f, 0.f}, ni[4] = {0.f, 0.f, 0.f, 0.f};
#pragma unroll
    for (int l = 0; l < 4; ++l) {
      int src = grp | l;
      float tlr = Tcr[l], tli = Tci[l];   // T[l,j] local (pre-update)
#pragma unroll
      for (int i = 0; i < 4; ++i) {
        float br = __shfl(Tcr[i], src);   // T[i,l]
        float bi = __shfl(Tci[i], src);
        nr[i] = fmaf(br, tlr, fmaf(-bi, tli, nr[i]));
        ni[i] = fmaf(br, tli, fmaf( bi, tlr, ni[i]));
      }
    }
#pragma unroll
    for (int i = 0; i < 4; ++i) { Tcr[i] = nr[i]; Tci[i] = ni[i]; }
  }
#pragma unroll
  for (int i = 0; i < 4; ++i)
    Ubuf[(size_t)pair * 16 + i * 4 + j] = make_float2(Tcr[i], Tci[i]);
}

// ---------------------------------------------------------------------------
// qsim helpers: 16-amp register groups.
// Contiguous group<S>: bits S+3..S.  Strided group: strides 2^9 and 2^5.
// ---------------------------------------------------------------------------
template<int S>
__device__ __forceinline__ int grpbase(int t) {
  return ((t >> S) << (S + 4)) | (t & ((1 << S) - 1));
}
template<int S>
__device__ __forceinline__ void ldgrp(const float2* st, int base, float* vr, float* vi) {
#pragma unroll
  for (int k = 0; k < 16; ++k) {
    float2 v = st[F2(base + (k << S))];
    vr[k] = v.x; vi[k] = v.y;
  }
}
template<int S>
__device__ __forceinline__ void stgrp(float2* st, int base, const float* vr, const float* vi) {
#pragma unroll
  for (int k = 0; k < 16; ++k) st[F2(base + (k << S))] = make_float2(vr[k], vi[k]);
}
// strided group: bits excluded {10,9} and {6,5}; base from t's 10 bits
__device__ __forceinline__ int base2s(int t) {
  return ((t >> 7) << 11) | (((t >> 5) & 3) << 7) | (t & 31);
}
__device__ __forceinline__ int addr2s(int base, int k) {
  return base + ((k >> 2) << 9) + ((k & 3) << 5);
}
__device__ __forceinline__ void ldgrp2(const float2* st, int base, float* vr, float* vi) {
#pragma unroll
  for (int k = 0; k < 16; ++k) {
    float2 v = st[F2(addr2s(base, k))];
    vr[k] = v.x; vi[k] = v.y;
  }
}
__device__ __forceinline__ void stgrp2(float2* st, int base, const float* vr, const float* vi) {
#pragma unroll
  for (int k = 0; k < 16; ++k) st[F2(addr2s(base, k))] = make_float2(vr[k], vi[k]);
}

__device__ __forceinline__ void loadU(const float2* __restrict__ Ug, float* ur, float* ui) {
#pragma unroll
  for (int e = 0; e < 16; ++e) {
    float2 u = Ug[e];
    ur[e] = sbc(u.x); ui[e] = sbc(u.y);
  }
}

// gate on local bits (3,2)
__device__ __forceinline__ void applyU_hi(float* vr, float* vi, const float* ur, const float* ui) {
#pragma unroll
  for (int j2 = 0; j2 < 4; ++j2) {
    float ar[4], ai[4];
#pragma unroll
    for (int j = 0; j < 4; ++j) { ar[j] = vr[4 * j + j2]; ai[j] = vi[4 * j + j2]; }
#pragma unroll
    for (int i = 0; i < 4; ++i) {
      float xr = 0.f, xi = 0.f;
#pragma unroll
      for (int j = 0; j < 4; ++j) {
        xr = fmaf(ur[4 * i + j], ar[j], fmaf(-ui[4 * i + j], ai[j], xr));
        xi = fmaf(ur[4 * i + j], ai[j], fmaf( ui[4 * i + j], ar[j], xi));
      }
      vr[4 * i + j2] = xr; vi[4 * i + j2] = xi;
    }
  }
}
// gate on local bits (1,0)
__device__ __forceinline__ void applyU_lo(float* vr, float* vi, const float* ur, const float* ui) {
#pragma unroll
  for (int i2 = 0; i2 < 4; ++i2) {
    float ar[4], ai[4];
#pragma unroll
    for (int j = 0; j < 4; ++j) { ar[j] = vr[4 * i2 + j]; ai[j] = vi[4 * i2 + j]; }
#pragma unroll
    for (int i = 0; i < 4; ++i) {
      float xr = 0.f, xi = 0.f;
#pragma unroll
      for (int j = 0; j < 4; ++j) {
        xr = fmaf(ur[4 * i + j], ar[j], fmaf(-ui[4 * i + j], ai[j], xr));
        xi = fmaf(ur[4 * i + j], ai[j], fmaf( ui[4 * i + j], ar[j], xi));
      }
      vr[4 * i2 + i] = xr; vi[4 * i2 + i] = xi;
    }
  }
}
// gate on local bits (2,1)
__device__ __forceinline__ void applyU_mid(float* vr, float* vi, const float* ur, const float* ui) {
#pragma unroll
  for (int o = 0; o < 4; ++o) {
    const int kb = ((o >> 1) << 3) | (o & 1);
    float ar[4], ai[4];
#pragma unroll
    for (int j = 0; j < 4; ++j) { ar[j] = vr[kb | (j << 1)]; ai[j] = vi[kb | (j << 1)]; }
#pragma unroll
    for (int i = 0; i < 4; ++i) {
      float xr = 0.f, xi = 0.f;
#pragma unroll
      for (int j = 0; j < 4; ++j) {
        xr = fmaf(ur[4 * i + j], ar[j], fmaf(-ui[4 * i + j], ai[j], xr));
        xi = fmaf(ur[4 * i + j], ai[j], fmaf( ui[4 * i + j], ar[j], xi));
      }
      vr[kb | (i << 1)] = xr; vi[kb | (i << 1)] = xi;
    }
  }
}

template<int B>
__device__ __forceinline__ void ry16(float* vr, float* vi, float c, float s) {
#pragma unroll
  for (int k = 0; k < 16; ++k) {
    if (!(k & (1 << B))) {
      const int k1 = k | (1 << B);
      float r0 = vr[k], i0 = vi[k], r1 = vr[k1], i1 = vi[k1];
      vr[k]  = fmaf(c, r0, -s * r1);  vi[k]  = fmaf(c, i0, -s * i1);
      vr[k1] = fmaf(s, r0,  c * r1);  vi[k1] = fmaf(s, i0,  c * i1);
    }
  }
}
template<int CB, int TB>
__device__ __forceinline__ void cx16(float* vr, float* vi) {
#pragma unroll
  for (int k = 0; k < 16; ++k) {
    if ((k & (1 << CB)) && !(k & (1 << TB))) {
      const int k1 = k | (1 << TB);
      float tr = vr[k]; vr[k] = vr[k1]; vr[k1] = tr;
      float ti = vi[k]; vi[k] = vi[k1]; vi[k1] = ti;
    }
  }
}

// encoding pass: 3 gates (hi,lo,mid) on contiguous group<S>
template<int S>
__device__ __forceinline__ void enc_pass3(float2* st, const float2* __restrict__ U,
                                          int gHi, int gLo, int gMid, int b, int t) {
  float ur[16], ui[16], vr[16], vi[16];
  int base = grpbase<S>(t);
  ldgrp<S>(st, base, vr, vi);
  loadU(U + ((size_t)gHi  * BATCH + b) * 16, ur, ui); applyU_hi (vr, vi, ur, ui);
  loadU(U + ((size_t)gLo  * BATCH + b) * 16, ur, ui); applyU_lo (vr, vi, ur, ui);
  loadU(U + ((size_t)gMid * BATCH + b) * 16, ur, ui); applyU_mid(vr, vi, ur, ui);
  stgrp<S>(st, base, vr, vi);
}
// encoding pass D: S=0, gates lo=(12,13) then mid=(11,12)
__device__ __forceinline__ void enc_passD(float2* st, const float2* __restrict__ U,
                                          int gLo, int gMid, int b, int t) {
  float ur[16], ui[16], vr[16], vi[16];
  int base = t << 4;
  ldgrp<0>(st, base, vr, vi);
  loadU(U + ((size_t)gLo  * BATCH + b) * 16, ur, ui); applyU_lo (vr, vi, ur, ui);
  loadU(U + ((size_t)gMid * BATCH + b) * 16, ur, ui); applyU_mid(vr, vi, ur, ui);
  stgrp<0>(st, base, vr, vi);
}
// encoding pass E: strided group, gates (3,4) on hi-role and (7,8) on lo-role
__device__ __forceinline__ void enc_passE(float2* st, const float2* __restrict__ U,
                                          int gA, int gB, int b, int t) {
  float ur[16], ui[16], vr[16], vi[16];
  int base = base2s(t);
  ldgrp2(st, base, vr, vi);
  loadU(U + ((size_t)gA * BATCH + b) * 16, ur, ui); applyU_hi(vr, vi, ur, ui);
  loadU(U + ((size_t)gB * BATCH + b) * 16, ur, ui); applyU_lo(vr, vi, ur, ui);
  stgrp2(st, base, vr, vi);
}
// variational pass: RY(q..q+3) + CXe(q,q+1),(q+2,q+3) + CXo(q+1,q+2)
template<int S>
__device__ __forceinline__ void var_pass3(float2* st, const float* __restrict__ vp,
                                          int l, int qbase, int t) {
  float vr[16], vi[16];
  int base = grpbase<S>(t);
  ldgrp<S>(st, base, vr, vi);
  float c[4], sn[4];
#pragma unroll
  for (int i = 0; i < 4; ++i) {
    float a = sbc(vp[l * NQ + qbase + i]) * 0.5f;
    c[i] = cosf(a); sn[i] = sinf(a);
  }
  ry16<3>(vr, vi, c[0], sn[0]);
  ry16<2>(vr, vi, c[1], sn[1]);
  ry16<1>(vr, vi, c[2], sn[2]);
  ry16<0>(vr, vi, c[3], sn[3]);
  cx16<3, 2>(vr, vi);   // CXe(q,q+1)
  cx16<1, 0>(vr, vi);   // CXe(q+2,q+3)
  cx16<2, 1>(vr, vi);   // CXo(q+1,q+2)
  stgrp<S>(st, base, vr, vi);
}
// variational pass D: S=0: RY(12),RY(13), CXe(12,13), CXo(11,12)
__device__ __forceinline__ void var_passD(float2* st, const float* __restrict__ vp,
                                          int l, int t) {
  float vr[16], vi[16];
  int base = t << 4;
  ldgrp<0>(st, base, vr, vi);
  float a0 = sbc(vp[l * NQ + 12]) * 0.5f;
  float a1 = sbc(vp[l * NQ + 13]) * 0.5f;
  ry16<1>(vr, vi, cosf(a0), sinf(a0));
  ry16<0>(vr, vi, cosf(a1), sinf(a1));
  cx16<1, 0>(vr, vi);   // CXe(12,13)
  cx16<2, 1>(vr, vi);   // CXo(11,12)
  stgrp<0>(st, base, vr, vi);
}
// variational pass E: strided; CXo(3,4) and CXo(7,8) (pure swaps)
__device__ __forceinline__ void var_passE(float2* st, int t) {
  float vr[16], vi[16];
  int base = base2s(t);
  ldgrp2(st, base, vr, vi);
  cx16<3, 2>(vr, vi);
  cx16<1, 0>(vr, vi);
  stgrp2(st, base, vr, vi);
}

// ---------------------------------------------------------------------------
// Kernel 3: full statevector sim, one block per batch element.
// ---------------------------------------------------------------------------
__global__ __launch_bounds__(1024) void qsim_kernel(
    const float2* __restrict__ U, const float* __restrict__ var_params,
    const float* __restrict__ A, const float* __restrict__ Bp,
    const float* __restrict__ D, const float* __restrict__ Wh,
    const float* __restrict__ bh, float* __restrict__ out)
{
  __shared__ float2 st[PHYS2];
  __shared__ float obsb[256];
  __shared__ float red[16];
  __shared__ float qv[NOBS];

  const int t = threadIdx.x;
  const int b = blockIdx.x;

  for (int i = t; i < PHYS2; i += 1024) st[i] = make_float2(0.f, 0.f);
  __syncthreads();
  if (t == 0) st[0] = make_float2(1.f, 0.f);
  __syncthreads();

  // ---- encoding: 2 blocks x 5 fused passes (13 gates each) ----
  for (int nb = 0; nb < 2; ++nb) {
    int gI = nb * 13;
    enc_pass3<10>(st, U, gI + 0, gI + 1, gI + 7,  b, t); __syncthreads();
    enc_pass3<6 >(st, U, gI + 2, gI + 3, gI + 9,  b, t); __syncthreads();
    enc_pass3<2 >(st, U, gI + 4, gI + 5, gI + 11, b, t); __syncthreads();
    enc_passD    (st, U, gI + 6, gI + 12,         b, t); __syncthreads();
    enc_passE    (st, U, gI + 8, gI + 10,         b, t); __syncthreads();
  }

  // ---- variational: 3 layers x 5 fused passes ----
  for (int l = 0; l < DEPTH; ++l) {
    var_pass3<10>(st, var_params, l, 0, t); __syncthreads();
    var_pass3<6 >(st, var_params, l, 4, t); __syncthreads();
    var_pass3<2 >(st, var_params, l, 8, t); __syncthreads();
    var_passD    (st, var_params, l,    t); __syncthreads();
    var_passE    (st, t);                   __syncthreads();
  }

  // ---- 11 Hermitian expectation values ----
  for (int w = 0; w < NOBS; ++w) {
    if (t < NOFF) obsb[t] = A[w * NOFF + t];
    else if (t < 2 * NOFF) obsb[t] = Bp[w * NOFF + (t - NOFF)];
    else if (t < 2 * NOFF + KDIM) obsb[t] = D[w * KDIM + (t - 2 * NOFF)];
    __syncthreads();

    int shift = 10 - w;
    int hi = t >> shift;
    int lo = t & ((1 << shift) - 1);
    int base2 = (hi << (shift + 4)) | lo;
    float sr[16], si[16];
#pragma unroll
    for (int k = 0; k < 16; ++k) {
      float2 v = st[F2(base2 + (k << shift))];
      sr[k] = v.x; si[k] = v.y;
    }
    float E = 0.f;
#pragma unroll
    for (int k = 0; k < 15; ++k)
      E = fmaf(obsb[240 + k + 1], sr[k] * sr[k] + si[k] * si[k], E);
#pragma unroll
    for (int k = 1; k < 16; ++k) {
#pragma unroll
      for (int l2 = 0; l2 < k; ++l2) {
        const int pidx = (k * (k - 1)) / 2 + l2;
        float t1 = sr[k] * sr[l2] + si[k] * si[l2];
        float t2 = si[k] * sr[l2] - sr[k] * si[l2];
        E = fmaf(obsb[pidx], t1, fmaf(obsb[NOFF + pidx], t2, E));
      }
    }
    E *= 2.0f;
#pragma unroll
    for (int off = 32; off; off >>= 1) E += __shfl_xor(E, off);
    if ((t & 63) == 0) red[t >> 6] = E;
    __syncthreads();
    if (t == 0) {
      float sum = 0.f;
      for (int ww = 0; ww < 16; ++ww) sum += red[ww];
      qv[w] = sum;
    }
    __syncthreads();
  }

  // ---- head ----
  if (t < OUTDIM) {
    float o = bh[t];
#pragma unroll
    for (int w = 0; w < NOBS; ++w) o = fmaf(Wh[t * NOBS + w], qv[w], o);
    out[b * OUTDIM + t] = o;
  }
}

extern "C" void kernel_launch(void* const* d_in, const int* in_sizes, int n_in,
                              void* d_out, int out_size, void* d_ws, size_t ws_size,
                              hipStream_t stream) {
  const float* x          = (const float*)d_in[0];
  const float* W_enc      = (const float*)d_in[1];
  const float* b_enc      = (const float*)d_in[2];
  const float* var_params = (const float*)d_in[3];
  const float* A          = (const float*)d_in[4];
  const float* Bp         = (const float*)d_in[5];
  const float* D          = (const float*)d_in[6];
  const float* W_head     = (const float*)d_in[7];
  const float* b_head     = (const float*)d_in[8];
  float* out = (float*)d_out;

  float*  theta = (float*)d_ws;                                    // 3328*15 f32
  size_t  thBytes = (size_t)3328 * 15 * sizeof(float);
  float2* Ubuf = (float2*)((char*)d_ws + ((thBytes + 255) / 256) * 256);

  enc_kernel <<<832, 256, 0, stream>>>(x, W_enc, b_enc, theta);
  expm_kernel<<<52,  256, 0, stream>>>(theta, Ubuf);
  qsim_kernel<<<128, 1024, 0, stream>>>(Ubuf, var_params, A, Bp, D,
                                        W_head, b_head, out);
}

// Round 4
// 182.118 us; speedup vs baseline: 1.5604x; 1.1389x over previous
//
#include <hip/hip_runtime.h>
#include <math.h>

#define NQ      14
#define NSTATE  16384
#define BATCH   128
#define DEPTH   3
#define NOBS    11
#define KDIM    16
#define NOFF    120
#define INDIM   784
#define OUTDIM  10

// skew on complex index: logical a -> physical a + (a>>4) (float2 units)
__device__ __forceinline__ int F2(int a) { return a + (a >> 4); }
#define PHYS2 (NSTATE + (NSTATE >> 4))   // 17408 float2 = 136 KB

// force block-uniform value into SGPR
__device__ __forceinline__ float sbc(float x) {
  return __int_as_float(__builtin_amdgcn_readfirstlane(__float_as_int(x)));
}

// ---------------------------------------------------------------------------
// Kernel 1: encoding GEMM. One wave per (g,b) pair -> theta[g*128+b][15].
// ---------------------------------------------------------------------------
__global__ __launch_bounds__(256) void enc_kernel(
    const float* __restrict__ x, const float* __restrict__ W,
    const float* __restrict__ bvec, float* __restrict__ theta)
{
  int wave = ((blockIdx.x << 2) | (threadIdx.x >> 6));   // 0..3327
  int lane = threadIdx.x & 63;
  int g = wave >> 7;
  int b = wave & 127;

  const float4* x4 = (const float4*)(x + (size_t)b * INDIM);        // 196 f4
  const float4* w4 = (const float4*)(W + (size_t)g * 15 * INDIM);

  float acc[15];
#pragma unroll
  for (int m = 0; m < 15; ++m) acc[m] = 0.f;
#pragma unroll
  for (int it = 0; it < 4; ++it) {
    int j4 = lane + it * 64;
    if (j4 < 196) {
      float4 xv = x4[j4];
#pragma unroll
      for (int m = 0; m < 15; ++m) {
        float4 wv = w4[m * 196 + j4];
        acc[m] = fmaf(xv.x, wv.x, fmaf(xv.y, wv.y, fmaf(xv.z, wv.z, fmaf(xv.w, wv.w, acc[m]))));
      }
    }
  }
#pragma unroll
  for (int m = 0; m < 15; ++m) {
#pragma unroll
    for (int off = 32; off; off >>= 1) acc[m] += __shfl_xor(acc[m], off);
  }
  if (lane == 0) {
#pragma unroll
    for (int m = 0; m < 15; ++m) theta[(size_t)wave * 15 + m] = acc[m] + bvec[g * 15 + m];
  }
}

// ---------------------------------------------------------------------------
// Kernel 2: U = expm(i * sum th_m P_m). FOUR lanes per matrix; lane j owns
// column j of T. G replicated per lane (Horner is lane-local); squarings
// fetch columns via intra-group shuffles.
// ---------------------------------------------------------------------------
__global__ __launch_bounds__(256) void expm_kernel(
    const float* __restrict__ theta, float2* __restrict__ Ubuf)
{
  int gid  = blockIdx.x * 256 + threadIdx.x;   // 0..13311
  int pair = gid >> 2;                         // 0..3327
  int j    = gid & 3;                          // column
  int lane = threadIdx.x & 63;
  int grp  = lane & 60;

  const float* th = theta + (size_t)pair * 15;

  const float pr_[4][4] = {{1,0,0,1},{0,1,1,0},{0,0,0,0},{1,0,0,-1}};
  const float pi_[4][4] = {{0,0,0,0},{0,0,0,0},{0,-1,1,0},{0,0,0,0}};

  float Hre[16], Him[16];
#pragma unroll
  for (int e = 0; e < 16; ++e) { Hre[e] = 0.f; Him[e] = 0.f; }
  float tsum = 0.f;
#pragma unroll
  for (int m = 0; m < 15; ++m) {
    float tv = th[m];
    tsum += fabsf(tv);
    const int code = m + 1;
    const int a = code >> 2, c = code & 3;
#pragma unroll
    for (int i = 0; i < 4; ++i)
#pragma unroll
      for (int jj = 0; jj < 4; ++jj) {
        float ar = pr_[a][(i >> 1) * 2 + (jj >> 1)], ai = pi_[a][(i >> 1) * 2 + (jj >> 1)];
        float br = pr_[c][(i & 1) * 2 + (jj & 1)],   bi = pi_[c][(i & 1) * 2 + (jj & 1)];
        Hre[i * 4 + jj] += tv * (ar * br - ai * bi);
        Him[i * 4 + jj] += tv * (ar * bi + ai * br);
      }
  }
  int s = 0;
  if (tsum > 0.25f) {
    s = (int)ceilf(log2f(tsum * 4.0f));
    if (s < 0) s = 0;
    if (s > 14) s = 14;
  }
  float sc = exp2f((float)(-s));
  // G = i*H*sc (full, replicated per lane)
  float Gre[16], Gim[16];
#pragma unroll
  for (int e = 0; e < 16; ++e) { Gre[e] = -Him[e] * sc; Gim[e] = Hre[e] * sc; }

  // column-j Horner: Tc = G[:,j]/9 + e_j;  Tc = e_j + (G/k)Tc, k=8..1
  float Tcr[4], Tci[4];
#pragma unroll
  for (int i = 0; i < 4; ++i) {
    Tcr[i] = Gre[i * 4 + j] * (1.f / 9.f) + ((i == j) ? 1.f : 0.f);
    Tci[i] = Gim[i * 4 + j] * (1.f / 9.f);
  }
#pragma unroll
  for (int k = 8; k >= 1; --k) {
    float nr[4], ni[4];
    float invk = 1.0f / (float)k;
#pragma unroll
    for (int i = 0; i < 4; ++i) {
      float xr = 0.f, xi = 0.f;
#pragma unroll
      for (int l = 0; l < 4; ++l) {
        xr = fmaf(Gre[i * 4 + l], Tcr[l], fmaf(-Gim[i * 4 + l], Tci[l], xr));
        xi = fmaf(Gre[i * 4 + l], Tci[l], fmaf( Gim[i * 4 + l], Tcr[l], xi));
      }
      nr[i] = invk * xr + ((i == j) ? 1.f : 0.f);
      ni[i] = invk * xi;
    }
#pragma unroll
    for (int i = 0; i < 4; ++i) { Tcr[i] = nr[i]; Tci[i] = ni[i]; }
  }
  // square s times: new[:,j] = sum_l T[:,l] * T[l,j]
  for (int it = 0; it < s; ++it) {
    float nr[4] = {0.f, 0.f, 0.f, 0.f}, ni[4] = {0.f, 0.f, 0.f, 0.f};
#pragma unroll
    for (int l = 0; l < 4; ++l) {
      int src = grp | l;
      float tlr = Tcr[l], tli = Tci[l];   // T[l,j] local (pre-update)
#pragma unroll
      for (int i = 0; i < 4; ++i) {
        float br = __shfl(Tcr[i], src);   // T[i,l]
        float bi = __shfl(Tci[i], src);
        nr[i] = fmaf(br, tlr, fmaf(-bi, tli, nr[i]));
        ni[i] = fmaf(br, tli, fmaf( bi, tlr, ni[i]));
      }
    }
#pragma unroll
    for (int i = 0; i < 4; ++i) { Tcr[i] = nr[i]; Tci[i] = ni[i]; }
  }
#pragma unroll
  for (int i = 0; i < 4; ++i)
    Ubuf[(size_t)pair * 16 + i * 4 + j] = make_float2(Tcr[i], Tci[i]);
}

// ---------------------------------------------------------------------------
// qsim helpers: 16-amp register groups.
// Contiguous group<S>: bits S+3..S.  Strided group: strides 2^9 and 2^5.
// ---------------------------------------------------------------------------
template<int S>
__device__ __forceinline__ int grpbase(int t) {
  return ((t >> S) << (S + 4)) | (t & ((1 << S) - 1));
}
template<int S>
__device__ __forceinline__ void ldgrp(const float2* st, int base, float* vr, float* vi) {
#pragma unroll
  for (int k = 0; k < 16; ++k) {
    float2 v = st[F2(base + (k << S))];
    vr[k] = v.x; vi[k] = v.y;
  }
}
template<int S>
__device__ __forceinline__ void stgrp(float2* st, int base, const float* vr, const float* vi) {
#pragma unroll
  for (int k = 0; k < 16; ++k) st[F2(base + (k << S))] = make_float2(vr[k], vi[k]);
}
// strided group: bits excluded {10,9} and {6,5}; base from t's 10 bits
__device__ __forceinline__ int base2s(int t) {
  return ((t >> 7) << 11) | (((t >> 5) & 3) << 7) | (t & 31);
}
__device__ __forceinline__ int addr2s(int base, int k) {
  return base + ((k >> 2) << 9) + ((k & 3) << 5);
}
__device__ __forceinline__ void ldgrp2(const float2* st, int base, float* vr, float* vi) {
#pragma unroll
  for (int k = 0; k < 16; ++k) {
    float2 v = st[F2(addr2s(base, k))];
    vr[k] = v.x; vi[k] = v.y;
  }
}
__device__ __forceinline__ void stgrp2(float2* st, int base, const float* vr, const float* vi) {
#pragma unroll
  for (int k = 0; k < 16; ++k) st[F2(addr2s(base, k))] = make_float2(vr[k], vi[k]);
}

__device__ __forceinline__ void loadU(const float2* __restrict__ Ug, float* ur, float* ui) {
#pragma unroll
  for (int e = 0; e < 16; ++e) {
    float2 u = Ug[e];
    ur[e] = sbc(u.x); ui[e] = sbc(u.y);
  }
}

// gate on local bits (3,2)
__device__ __forceinline__ void applyU_hi(float* vr, float* vi, const float* ur, const float* ui) {
#pragma unroll
  for (int j2 = 0; j2 < 4; ++j2) {
    float ar[4], ai[4];
#pragma unroll
    for (int j = 0; j < 4; ++j) { ar[j] = vr[4 * j + j2]; ai[j] = vi[4 * j + j2]; }
#pragma unroll
    for (int i = 0; i < 4; ++i) {
      float xr = 0.f, xi = 0.f;
#pragma unroll
      for (int j = 0; j < 4; ++j) {
        xr = fmaf(ur[4 * i + j], ar[j], fmaf(-ui[4 * i + j], ai[j], xr));
        xi = fmaf(ur[4 * i + j], ai[j], fmaf( ui[4 * i + j], ar[j], xi));
      }
      vr[4 * i + j2] = xr; vi[4 * i + j2] = xi;
    }
  }
}
// gate on local bits (1,0)
__device__ __forceinline__ void applyU_lo(float* vr, float* vi, const float* ur, const float* ui) {
#pragma unroll
  for (int i2 = 0; i2 < 4; ++i2) {
    float ar[4], ai[4];
#pragma unroll
    for (int j = 0; j < 4; ++j) { ar[j] = vr[4 * i2 + j]; ai[j] = vi[4 * i2 + j]; }
#pragma unroll
    for (int i = 0; i < 4; ++i) {
      float xr = 0.f, xi = 0.f;
#pragma unroll
      for (int j = 0; j < 4; ++j) {
        xr = fmaf(ur[4 * i + j], ar[j], fmaf(-ui[4 * i + j], ai[j], xr));
        xi = fmaf(ur[4 * i + j], ai[j], fmaf( ui[4 * i + j], ar[j], xi));
      }
      vr[4 * i2 + i] = xr; vi[4 * i2 + i] = xi;
    }
  }
}
// gate on local bits (2,1)
__device__ __forceinline__ void applyU_mid(float* vr, float* vi, const float* ur, const float* ui) {
#pragma unroll
  for (int o = 0; o < 4; ++o) {
    const int kb = ((o >> 1) << 3) | (o & 1);
    float ar[4], ai[4];
#pragma unroll
    for (int j = 0; j < 4; ++j) { ar[j] = vr[kb | (j << 1)]; ai[j] = vi[kb | (j << 1)]; }
#pragma unroll
    for (int i = 0; i < 4; ++i) {
      float xr = 0.f, xi = 0.f;
#pragma unroll
      for (int j = 0; j < 4; ++j) {
        xr = fmaf(ur[4 * i + j], ar[j], fmaf(-ui[4 * i + j], ai[j], xr));
        xi = fmaf(ur[4 * i + j], ai[j], fmaf( ui[4 * i + j], ar[j], xi));
      }
      vr[kb | (i << 1)] = xr; vi[kb | (i << 1)] = xi;
    }
  }
}

template<int B>
__device__ __forceinline__ void ry16(float* vr, float* vi, float c, float s) {
#pragma unroll
  for (int k = 0; k < 16; ++k) {
    if (!(k & (1 << B))) {
      const int k1 = k | (1 << B);
      float r0 = vr[k], i0 = vi[k], r1 = vr[k1], i1 = vi[k1];
      vr[k]  = fmaf(c, r0, -s * r1);  vi[k]  = fmaf(c, i0, -s * i1);
      vr[k1] = fmaf(s, r0,  c * r1);  vi[k1] = fmaf(s, i0,  c * i1);
    }
  }
}
template<int CB, int TB>
__device__ __forceinline__ void cx16(float* vr, float* vi) {
#pragma unroll
  for (int k = 0; k < 16; ++k) {
    if ((k & (1 << CB)) && !(k & (1 << TB))) {
      const int k1 = k | (1 << TB);
      float tr = vr[k]; vr[k] = vr[k1]; vr[k1] = tr;
      float ti = vi[k]; vi[k] = vi[k1]; vi[k1] = ti;
    }
  }
}

// encoding pass: 3 gates (hi,lo,mid) on contiguous group<S>
template<int S>
__device__ __forceinline__ void enc_pass3(float2* st, const float2* __restrict__ U,
                                          int gHi, int gLo, int gMid, int b, int t) {
  float ur[16], ui[16], vr[16], vi[16];
  int base = grpbase<S>(t);
  ldgrp<S>(st, base, vr, vi);
  loadU(U + ((size_t)gHi  * BATCH + b) * 16, ur, ui); applyU_hi (vr, vi, ur, ui);
  loadU(U + ((size_t)gLo  * BATCH + b) * 16, ur, ui); applyU_lo (vr, vi, ur, ui);
  loadU(U + ((size_t)gMid * BATCH + b) * 16, ur, ui); applyU_mid(vr, vi, ur, ui);
  stgrp<S>(st, base, vr, vi);
}
// encoding pass D: S=0, gates lo=(12,13) then mid=(11,12)
__device__ __forceinline__ void enc_passD(float2* st, const float2* __restrict__ U,
                                          int gLo, int gMid, int b, int t) {
  float ur[16], ui[16], vr[16], vi[16];
  int base = t << 4;
  ldgrp<0>(st, base, vr, vi);
  loadU(U + ((size_t)gLo  * BATCH + b) * 16, ur, ui); applyU_lo (vr, vi, ur, ui);
  loadU(U + ((size_t)gMid * BATCH + b) * 16, ur, ui); applyU_mid(vr, vi, ur, ui);
  stgrp<0>(st, base, vr, vi);
}
// encoding pass E: strided group, gates (3,4) on hi-role and (7,8) on lo-role
__device__ __forceinline__ void enc_passE(float2* st, const float2* __restrict__ U,
                                          int gA, int gB, int b, int t) {
  float ur[16], ui[16], vr[16], vi[16];
  int base = base2s(t);
  ldgrp2(st, base, vr, vi);
  loadU(U + ((size_t)gA * BATCH + b) * 16, ur, ui); applyU_hi(vr, vi, ur, ui);
  loadU(U + ((size_t)gB * BATCH + b) * 16, ur, ui); applyU_lo(vr, vi, ur, ui);
  stgrp2(st, base, vr, vi);
}
// variational pass: RY(q..q+3) + CXe(q,q+1),(q+2,q+3) + CXo(q+1,q+2)
template<int S>
__device__ __forceinline__ void var_pass3(float2* st, const float* __restrict__ vp,
                                          int l, int qbase, int t) {
  float vr[16], vi[16];
  int base = grpbase<S>(t);
  ldgrp<S>(st, base, vr, vi);
  float c[4], sn[4];
#pragma unroll
  for (int i = 0; i < 4; ++i) {
    float a = sbc(vp[l * NQ + qbase + i]) * 0.5f;
    c[i] = cosf(a); sn[i] = sinf(a);
  }
  ry16<3>(vr, vi, c[0], sn[0]);
  ry16<2>(vr, vi, c[1], sn[1]);
  ry16<1>(vr, vi, c[2], sn[2]);
  ry16<0>(vr, vi, c[3], sn[3]);
  cx16<3, 2>(vr, vi);   // CXe(q,q+1)
  cx16<1, 0>(vr, vi);   // CXe(q+2,q+3)
  cx16<2, 1>(vr, vi);   // CXo(q+1,q+2)
  stgrp<S>(st, base, vr, vi);
}
// variational pass D: S=0: RY(12),RY(13), CXe(12,13), CXo(11,12)
__device__ __forceinline__ void var_passD(float2* st, const float* __restrict__ vp,
                                          int l, int t) {
  float vr[16], vi[16];
  int base = t << 4;
  ldgrp<0>(st, base, vr, vi);
  float a0 = sbc(vp[l * NQ + 12]) * 0.5f;
  float a1 = sbc(vp[l * NQ + 13]) * 0.5f;
  ry16<1>(vr, vi, cosf(a0), sinf(a0));
  ry16<0>(vr, vi, cosf(a1), sinf(a1));
  cx16<1, 0>(vr, vi);   // CXe(12,13)
  cx16<2, 1>(vr, vi);   // CXo(11,12)
  stgrp<0>(st, base, vr, vi);
}
// variational pass E: strided; CXo(3,4) and CXo(7,8) (pure swaps)
__device__ __forceinline__ void var_passE(float2* st, int t) {
  float vr[16], vi[16];
  int base = base2s(t);
  ldgrp2(st, base, vr, vi);
  cx16<3, 2>(vr, vi);
  cx16<1, 0>(vr, vi);
  stgrp2(st, base, vr, vi);
}

// ---------------------------------------------------------------------------
// Kernel 3: statevector sim. TWO blocks per batch element (redundant gate
// evolution on otherwise-idle CUs); obs phase split by w-parity.
// ---------------------------------------------------------------------------
__global__ __launch_bounds__(1024) void qsim_kernel(
    const float2* __restrict__ U, const float* __restrict__ var_params,
    const float* __restrict__ A, const float* __restrict__ Bp,
    const float* __restrict__ D, const float* __restrict__ Wh,
    const float* __restrict__ bh, float* __restrict__ out)
{
  __shared__ float2 st[PHYS2];
  __shared__ float obsa[6 * 256];    // A/B/D for up to 6 observables
  __shared__ float red[6][16];       // per-(obs, wave) partials

  const int t = threadIdx.x;
  const int b = blockIdx.x >> 1;
  const int h = blockIdx.x & 1;      // obs parity this block handles
  const int nw = h ? 5 : 6;

  for (int i = t; i < PHYS2; i += 1024)
    st[i] = (i == 0) ? make_float2(1.f, 0.f) : make_float2(0.f, 0.f);
  __syncthreads();

  // ---- encoding: 2 blocks x 5 fused passes (13 gates each) ----
  for (int nb = 0; nb < 2; ++nb) {
    int gI = nb * 13;
    enc_pass3<10>(st, U, gI + 0, gI + 1, gI + 7,  b, t); __syncthreads();
    enc_pass3<6 >(st, U, gI + 2, gI + 3, gI + 9,  b, t); __syncthreads();
    enc_pass3<2 >(st, U, gI + 4, gI + 5, gI + 11, b, t); __syncthreads();
    enc_passD    (st, U, gI + 6, gI + 12,         b, t); __syncthreads();
    enc_passE    (st, U, gI + 8, gI + 10,         b, t); __syncthreads();
  }

  // ---- variational: 3 layers x 5 fused passes ----
  for (int l = 0; l < DEPTH; ++l) {
    var_pass3<10>(st, var_params, l, 0, t); __syncthreads();
    var_pass3<6 >(st, var_params, l, 4, t); __syncthreads();
    var_pass3<2 >(st, var_params, l, 8, t); __syncthreads();
    var_passD    (st, var_params, l,    t); __syncthreads();
    var_passE    (st, t);                   __syncthreads();
  }

  // ---- stage observable params for my w's (w = 2*idx + h) ----
  for (int i = t; i < nw * 256; i += 1024) {
    int idx = i >> 8, off = i & 255, w = 2 * idx + h;
    float v;
    if (off < NOFF)            v = A[w * NOFF + off];
    else if (off < 2 * NOFF)   v = Bp[w * NOFF + (off - NOFF)];
    else if (off < 2 * NOFF + KDIM) v = D[w * KDIM + (off - 2 * NOFF)];
    else v = 0.f;
    obsa[i] = v;
  }
  __syncthreads();

  // ---- expectation values, barrier-free across w's ----
  const int wave = t >> 6;
  for (int idx = 0; idx < nw; ++idx) {
    const int w = 2 * idx + h;
    const float* ob = &obsa[idx << 8];
    int shift = 10 - w;
    int hi2 = t >> shift;
    int lo = t & ((1 << shift) - 1);
    int base2 = (hi2 << (shift + 4)) | lo;
    float sr[16], si[16];
#pragma unroll
    for (int k = 0; k < 16; ++k) {
      float2 v = st[F2(base2 + (k << shift))];
      sr[k] = v.x; si[k] = v.y;
    }
    float E = 0.f;
#pragma unroll
    for (int k = 0; k < 15; ++k)
      E = fmaf(ob[240 + k + 1], sr[k] * sr[k] + si[k] * si[k], E);
#pragma unroll
    for (int k = 1; k < 16; ++k) {
#pragma unroll
      for (int l2 = 0; l2 < k; ++l2) {
        const int pidx = (k * (k - 1)) / 2 + l2;
        float t1 = sr[k] * sr[l2] + si[k] * si[l2];
        float t2 = si[k] * sr[l2] - sr[k] * si[l2];
        E = fmaf(ob[pidx], t1, fmaf(ob[NOFF + pidx], t2, E));
      }
    }
    E *= 2.0f;
#pragma unroll
    for (int off = 32; off; off >>= 1) E += __shfl_xor(E, off);
    if ((t & 63) == 0) red[idx][wave] = E;
  }
  __syncthreads();

  // ---- head: partial contribution, accumulated atomically ----
  if (t < OUTDIM) {
    float o = (h == 0) ? bh[t] : 0.f;
    for (int idx = 0; idx < nw; ++idx) {
      const int w = 2 * idx + h;
      float q = 0.f;
#pragma unroll
      for (int ww = 0; ww < 16; ++ww) q += red[idx][ww];
      o = fmaf(Wh[t * NOBS + w], q, o);
    }
    atomicAdd(&out[b * OUTDIM + t], o);
  }
}

extern "C" void kernel_launch(void* const* d_in, const int* in_sizes, int n_in,
                              void* d_out, int out_size, void* d_ws, size_t ws_size,
                              hipStream_t stream) {
  const float* x          = (const float*)d_in[0];
  const float* W_enc      = (const float*)d_in[1];
  const float* b_enc      = (const float*)d_in[2];
  const float* var_params = (const float*)d_in[3];
  const float* A          = (const float*)d_in[4];
  const float* Bp         = (const float*)d_in[5];
  const float* D          = (const float*)d_in[6];
  const float* W_head     = (const float*)d_in[7];
  const float* b_head     = (const float*)d_in[8];
  float* out = (float*)d_out;

  float*  theta = (float*)d_ws;                                    // 3328*15 f32
  size_t  thBytes = (size_t)3328 * 15 * sizeof(float);
  float2* Ubuf = (float2*)((char*)d_ws + ((thBytes + 255) / 256) * 256);

  hipMemsetAsync(out, 0, (size_t)out_size * sizeof(float), stream);
  enc_kernel <<<832, 256, 0, stream>>>(x, W_enc, b_enc, theta);
  expm_kernel<<<52,  256, 0, stream>>>(theta, Ubuf);
  qsim_kernel<<<256, 1024, 0, stream>>>(Ubuf, var_params, A, Bp, D,
                                        W_head, b_head, out);
}